// Round 3
// baseline (959.110 us; speedup 1.0000x reference)
//
#include <hip/hip_runtime.h>

#define NB   16       // batches
#define NN   10000    // nodes per batch
#define NE   160000   // edges per batch
#define NODES (NB*NN) // 160000 total nodes
#define IN_F 19
#define HF   64
#define OUTF 32
#define LN_EPS 1e-5f
#define TPB  128      // threads/block for dense kernels: 32KB LDS -> 5 blocks/CU

// Key structure note (R3): dynamically-indexed per-thread arrays spill to
// scratch (R2: enc VGPR_Count=44, WRITE_SIZE 116MB vs 41MB useful). Fix:
// each thread keeps its dynamic-k input vector in an LDS column
// col[k*TPB + t] -- dynamic indexing is fine in LDS, 2 lanes/bank aliasing
// is free, and no __syncthreads is needed (thread reads only its own
// column). Accumulators are constant-indexed -> stay in VGPRs. Weight rows
// are wave-uniform -> s_load -> v_fmac with SGPR operand.

// ---------------- encoder: x = relu(nf@W1+b1)@W2+b2, thread per node ----------------
__global__ __launch_bounds__(TPB) void enc_kernel(
    const float* __restrict__ nf,
    const float* __restrict__ w1, const float* __restrict__ b1,
    const float* __restrict__ w2, const float* __restrict__ b2,
    float* __restrict__ x)
{
    __shared__ float col[HF * TPB];              // 32 KB, per-thread columns
    int t = threadIdx.x;
    int node = blockIdx.x * TPB + t;             // 1250*128 = 160000 exactly

    const float* p = nf + (size_t)node * IN_F;
    float a[IN_F];
#pragma unroll
    for (int k = 0; k < IN_F; ++k) a[k] = p[k];

    // layer 1: fully unrolled (k constant -> a[] stays in VGPRs)
    float h[HF];
#pragma unroll
    for (int j = 0; j < HF; ++j) h[j] = b1[j];
#pragma unroll
    for (int k = 0; k < IN_F; ++k) {
        float ak = a[k];
        const float* wr = w1 + k * HF;           // wave-uniform -> s_load
#pragma unroll
        for (int j = 0; j < HF; ++j) h[j] = fmaf(ak, wr[j], h[j]);
    }

    // relu + park h in this thread's LDS column for dynamic-k layer 2
#pragma unroll
    for (int j = 0; j < HF; ++j) col[j * TPB + t] = fmaxf(h[j], 0.f);

    float o[HF];
#pragma unroll
    for (int j = 0; j < HF; ++j) o[j] = b2[j];
#pragma unroll 1
    for (int k = 0; k < HF; ++k) {
        float v = col[k * TPB + t];
        const float* wr = w2 + k * HF;
#pragma unroll
        for (int j = 0; j < HF; ++j) o[j] = fmaf(v, wr[j], o[j]);
    }

    float4* dst = (float4*)(x + (size_t)node * HF);
#pragma unroll
    for (int q = 0; q < 16; ++q) {
        float4 v; v.x = o[4*q]; v.y = o[4*q+1]; v.z = o[4*q+2]; v.w = o[4*q+3];
        dst[q] = v;
    }
}

// ---------------- CSR build (XCD-affine grids: b = blockIdx%16) ----------------
__global__ __launch_bounds__(256) void hist_kernel(const int* __restrict__ ei, int* __restrict__ cnt)
{
    int b = blockIdx.x & 15;
    int e = (blockIdx.x >> 4) * 256 + threadIdx.x;   // 625 chunks * 256 = 160000
    int d = ei[(size_t)b * 2 * NE + NE + e];
    atomicAdd(&cnt[b * NN + d], 1);
}

__global__ __launch_bounds__(256) void scan_kernel(const int* __restrict__ cnt, int* __restrict__ off)
{
    __shared__ int sdata[256];
    int b = blockIdx.x, t = threadIdx.x;
    const int CH = 40;                          // 256*40 = 10240 >= NN
    int lo = t * CH, hi = min(lo + CH, NN);
    int s = 0;
    for (int i = lo; i < hi; ++i) s += cnt[b * NN + i];
    sdata[t] = s;
    __syncthreads();
    for (int ofs = 1; ofs < 256; ofs <<= 1) {
        int v = (t >= ofs) ? sdata[t - ofs] : 0;
        __syncthreads();
        sdata[t] += v;
        __syncthreads();
    }
    int run = (t > 0) ? sdata[t - 1] : 0;       // exclusive prefix
    for (int i = lo; i < hi; ++i) { off[b * NN + i] = run; run += cnt[b * NN + i]; }
}

__global__ __launch_bounds__(256) void fill_kernel(const int* __restrict__ ei,
                                                   const int* __restrict__ off,
                                                   int* __restrict__ cursor,
                                                   int* __restrict__ csr)
{
    int b = blockIdx.x & 15;
    int e = (blockIdx.x >> 4) * 256 + threadIdx.x;
    const int* eb = ei + (size_t)b * 2 * NE;
    int s = eb[e];
    int d = eb[NE + e];
    int pos = atomicAdd(&cursor[b * NN + d], 1);
    csr[(size_t)b * NE + off[b * NN + d] + pos] = s;
}

// ---------------- mean aggregation: wave per node, lane per channel ----------------
__global__ __launch_bounds__(256) void agg_kernel(const float* __restrict__ x,
                                                  const int* __restrict__ cnt,
                                                  const int* __restrict__ off,
                                                  const int* __restrict__ csr,
                                                  float* __restrict__ agg)
{
    int b = blockIdx.x & 15;                        // XCD affinity
    int chunk = blockIdx.x >> 4;                    // 0..2499
    int wid = threadIdx.x >> 6;                     // 4 waves = 4 nodes per block
    int n = chunk * 4 + wid;                        // 0..9999
    int w = b * NN + n;
    w = __builtin_amdgcn_readfirstlane(w);          // force wave-uniform -> scalar loads
    int lane = threadIdx.x & 63;
    int c = cnt[w];
    int o = off[w];
    const int* row = csr + (size_t)b * NE + o;
    const float* xb = x + (size_t)b * NN * HF;
    float s = 0.f;
    int t = 0;
    for (; t + 4 <= c; t += 4) {
        int i0 = row[t], i1 = row[t+1], i2 = row[t+2], i3 = row[t+3];
        s += xb[(size_t)i0 * HF + lane];
        s += xb[(size_t)i1 * HF + lane];
        s += xb[(size_t)i2 * HF + lane];
        s += xb[(size_t)i3 * HF + lane];
    }
    for (; t < c; ++t) s += xb[(size_t)row[t] * HF + lane];
    agg[(size_t)w * HF + lane] = (c > 0) ? s / (float)c : 0.f;
}

// ---------------- conv transform: [x,agg]@W + b, +residual, LN, relu (in-place) ----------------
__global__ __launch_bounds__(TPB) void conv_kernel(
    float* __restrict__ x, const float* __restrict__ agg,
    const float* __restrict__ W, const float* __restrict__ bias,
    const float* __restrict__ g, const float* __restrict__ beta)
{
    __shared__ float col[HF * TPB];              // 32 KB; reused for agg then x
    int t = threadIdx.x;
    int node = blockIdx.x * TPB + t;

    float acc[HF];
#pragma unroll
    for (int j = 0; j < HF; ++j) acc[j] = bias[j];

    // ---- agg half: W rows 64..127 ----
    const float4* ap = (const float4*)(agg + (size_t)node * HF);
#pragma unroll
    for (int q = 0; q < 16; ++q) {
        float4 v = ap[q];
        col[(4*q+0) * TPB + t] = v.x;
        col[(4*q+1) * TPB + t] = v.y;
        col[(4*q+2) * TPB + t] = v.z;
        col[(4*q+3) * TPB + t] = v.w;
    }
#pragma unroll 1
    for (int k = 0; k < HF; ++k) {
        float v = col[k * TPB + t];
        const float* wr = W + (HF + k) * HF;
#pragma unroll
        for (int j = 0; j < HF; ++j) acc[j] = fmaf(v, wr[j], acc[j]);
    }

    // ---- x half: W rows 0..63 (no sync needed: thread-private column) ----
    const float4* xp = (const float4*)(x + (size_t)node * HF);
#pragma unroll
    for (int q = 0; q < 16; ++q) {
        float4 v = xp[q];
        col[(4*q+0) * TPB + t] = v.x;
        col[(4*q+1) * TPB + t] = v.y;
        col[(4*q+2) * TPB + t] = v.z;
        col[(4*q+3) * TPB + t] = v.w;
    }
#pragma unroll 1
    for (int k = 0; k < HF; ++k) {
        float v = col[k * TPB + t];
        const float* wr = W + k * HF;
#pragma unroll
        for (int j = 0; j < HF; ++j) acc[j] = fmaf(v, wr[j], acc[j]);
    }

    // residual (x still parked in col) + LayerNorm + relu
    float mu = 0.f;
#pragma unroll
    for (int j = 0; j < HF; ++j) { acc[j] += col[j * TPB + t]; mu += acc[j]; }
    mu *= (1.f / HF);
    float var = 0.f;
#pragma unroll
    for (int j = 0; j < HF; ++j) { float d = acc[j] - mu; var += d * d; }
    var *= (1.f / HF);
    float rs = rsqrtf(var + LN_EPS);
#pragma unroll
    for (int j = 0; j < HF; ++j) {
        float y = (acc[j] - mu) * rs * g[j] + beta[j];
        acc[j] = fmaxf(y, 0.f);
    }

    float4* dst = (float4*)(x + (size_t)node * HF);
#pragma unroll
    for (int q = 0; q < 16; ++q) {
        float4 v; v.x = acc[4*q]; v.y = acc[4*q+1]; v.z = acc[4*q+2]; v.w = acc[4*q+3];
        dst[q] = v;
    }
}

// ---------------- output head: x@out_w + out_b ----------------
__global__ __launch_bounds__(TPB) void out_kernel(const float* __restrict__ x,
                                                  const float* __restrict__ W,
                                                  const float* __restrict__ bias,
                                                  float* __restrict__ out)
{
    __shared__ float col[HF * TPB];              // 32 KB
    int t = threadIdx.x;
    int node = blockIdx.x * TPB + t;

    const float4* xp = (const float4*)(x + (size_t)node * HF);
#pragma unroll
    for (int q = 0; q < 16; ++q) {
        float4 v = xp[q];
        col[(4*q+0) * TPB + t] = v.x;
        col[(4*q+1) * TPB + t] = v.y;
        col[(4*q+2) * TPB + t] = v.z;
        col[(4*q+3) * TPB + t] = v.w;
    }
    float o[OUTF];
#pragma unroll
    for (int j = 0; j < OUTF; ++j) o[j] = bias[j];
#pragma unroll 1
    for (int k = 0; k < HF; ++k) {
        float v = col[k * TPB + t];
        const float* wr = W + k * OUTF;
#pragma unroll
        for (int j = 0; j < OUTF; ++j) o[j] = fmaf(v, wr[j], o[j]);
    }
    float4* dst = (float4*)(out + (size_t)node * OUTF);
#pragma unroll
    for (int q = 0; q < 8; ++q) {
        float4 v; v.x = o[4*q]; v.y = o[4*q+1]; v.z = o[4*q+2]; v.w = o[4*q+3];
        dst[q] = v;
    }
}

extern "C" void kernel_launch(void* const* d_in, const int* in_sizes, int n_in,
                              void* d_out, int out_size, void* d_ws, size_t ws_size,
                              hipStream_t stream)
{
    const float* nf     = (const float*)d_in[0];
    const int*   ei     = (const int*)  d_in[1];   // edge_indices (B,2,E), integer
    const float* enc_w1 = (const float*)d_in[3];
    const float* enc_b1 = (const float*)d_in[4];
    const float* enc_w2 = (const float*)d_in[5];
    const float* enc_b2 = (const float*)d_in[6];
    const float* conv_w = (const float*)d_in[7];   // (3,128,64)
    const float* conv_b = (const float*)d_in[8];   // (3,64)
    const float* ln_g   = (const float*)d_in[9];
    const float* ln_b   = (const float*)d_in[10];
    const float* out_w  = (const float*)d_in[11];  // (64,32)
    const float* out_b  = (const float*)d_in[12];

    // workspace layout (~94 MB)
    char* w = (char*)d_ws;
    float* x    = (float*)w; w += (size_t)NODES * HF * sizeof(float);   // 40.96 MB
    float* agg  = (float*)w; w += (size_t)NODES * HF * sizeof(float);   // 40.96 MB
    int* cnt    = (int*)w;   w += (size_t)NODES * sizeof(int);
    int* cursor = (int*)w;   w += (size_t)NODES * sizeof(int);          // adjacent to cnt
    int* off    = (int*)w;   w += (size_t)NODES * sizeof(int);
    int* csr    = (int*)w;                                              // 10.24 MB

    // zero cnt+cursor (one contiguous memset; ws is poisoned 0xAA every call)
    hipMemsetAsync(cnt, 0, (size_t)NODES * 2 * sizeof(int), stream);

    enc_kernel<<<NODES / TPB, TPB, 0, stream>>>(nf, enc_w1, enc_b1, enc_w2, enc_b2, x);
    hist_kernel<<<NB * (NE / 256), 256, 0, stream>>>(ei, cnt);
    scan_kernel<<<NB, 256, 0, stream>>>(cnt, off);
    fill_kernel<<<NB * (NE / 256), 256, 0, stream>>>(ei, off, cursor, csr);

    for (int l = 0; l < 3; ++l) {
        agg_kernel<<<NODES / 4, 256, 0, stream>>>(x, cnt, off, csr, agg);
        conv_kernel<<<NODES / TPB, TPB, 0, stream>>>(x, agg,
                                                     conv_w + (size_t)l * 2 * HF * HF,
                                                     conv_b + (size_t)l * HF,
                                                     ln_g + (size_t)l * HF,
                                                     ln_b + (size_t)l * HF);
    }
    out_kernel<<<NODES / TPB, TPB, 0, stream>>>(x, out_w, out_b, (float*)d_out);
}

// Round 4
// 792.568 us; speedup vs baseline: 1.2101x; 1.2101x over previous
//
#include <hip/hip_runtime.h>

#define NB   16       // batches
#define NN   10000    // nodes per batch
#define NE   160000   // edges per batch
#define NODES (NB*NN) // 160000 total nodes
#define IN_F 19
#define HF   64
#define OUTF 32
#define LN_EPS 1e-5f

// R4 structure note: dynamic per-thread arrays spill (R2, 44 VGPR + 116MB
// scratch traffic); LDS columns serialize on lgkmcnt latency (R3, VALUBusy
// 16%). Fix: chunk the k-loop by 8 -- load two float4s from the thread's own
// row in GLOBAL (L1-resident, vmcnt-pipelined), av[8] is constant-indexed in
// the unrolled 8x64 FMA body, accumulators stay in VGPRs, weight rows are
// wave-uniform -> s_load -> v_fmac with SGPR operand. No LDS, ~100 VGPR ->
// 5 waves/SIMD.

// ---------------- enc1: h = relu(nf@W1+b1), fully unrolled (k=19 const) ----------------
__global__ __launch_bounds__(256) void enc1_kernel(
    const float* __restrict__ nf,
    const float* __restrict__ w1, const float* __restrict__ b1,
    float* __restrict__ x)
{
    int node = blockIdx.x * 256 + threadIdx.x;   // 625*256 = 160000 exactly
    const float* p = nf + (size_t)node * IN_F;
    float a[IN_F];
#pragma unroll
    for (int k = 0; k < IN_F; ++k) a[k] = p[k];

    float h[HF];
#pragma unroll
    for (int j = 0; j < HF; ++j) h[j] = b1[j];
#pragma unroll
    for (int k = 0; k < IN_F; ++k) {
        float ak = a[k];
        const float* wr = w1 + k * HF;           // wave-uniform -> s_load
#pragma unroll
        for (int j = 0; j < HF; ++j) h[j] = fmaf(ak, wr[j], h[j]);
    }

    float4* dst = (float4*)(x + (size_t)node * HF);
#pragma unroll
    for (int q = 0; q < 16; ++q) {
        float4 v;
        v.x = fmaxf(h[4*q],   0.f); v.y = fmaxf(h[4*q+1], 0.f);
        v.z = fmaxf(h[4*q+2], 0.f); v.w = fmaxf(h[4*q+3], 0.f);
        dst[q] = v;
    }
}

// ---------------- gemm64: x = x @ W + b, in-place (row is thread-private) ----------------
__global__ __launch_bounds__(256) void gemm64_kernel(
    float* __restrict__ x, const float* __restrict__ W, const float* __restrict__ bias)
{
    int node = blockIdx.x * 256 + threadIdx.x;
    const float* row = x + (size_t)node * HF;

    float acc[HF];
#pragma unroll
    for (int j = 0; j < HF; ++j) acc[j] = bias[j];

#pragma unroll 1
    for (int kc = 0; kc < HF; kc += 8) {
        float4 v0 = *(const float4*)(row + kc);
        float4 v1 = *(const float4*)(row + kc + 4);
        float av[8] = {v0.x, v0.y, v0.z, v0.w, v1.x, v1.y, v1.z, v1.w};
#pragma unroll
        for (int u = 0; u < 8; ++u) {
            const float* wr = W + (kc + u) * HF;
#pragma unroll
            for (int j = 0; j < HF; ++j) acc[j] = fmaf(av[u], wr[j], acc[j]);
        }
    }

    float4* dst = (float4*)(x + (size_t)node * HF);
#pragma unroll
    for (int q = 0; q < 16; ++q) {
        float4 v; v.x = acc[4*q]; v.y = acc[4*q+1]; v.z = acc[4*q+2]; v.w = acc[4*q+3];
        dst[q] = v;
    }
}

// ---------------- CSR build (unchanged this round) ----------------
__global__ __launch_bounds__(256) void hist_kernel(const int* __restrict__ ei, int* __restrict__ cnt)
{
    int b = blockIdx.x & 15;
    int e = (blockIdx.x >> 4) * 256 + threadIdx.x;   // 625 chunks * 256 = 160000
    int d = ei[(size_t)b * 2 * NE + NE + e];
    atomicAdd(&cnt[b * NN + d], 1);
}

__global__ __launch_bounds__(256) void scan_kernel(const int* __restrict__ cnt, int* __restrict__ off)
{
    __shared__ int sdata[256];
    int b = blockIdx.x, t = threadIdx.x;
    const int CH = 40;                          // 256*40 = 10240 >= NN
    int lo = t * CH, hi = min(lo + CH, NN);
    int s = 0;
    for (int i = lo; i < hi; ++i) s += cnt[b * NN + i];
    sdata[t] = s;
    __syncthreads();
    for (int ofs = 1; ofs < 256; ofs <<= 1) {
        int v = (t >= ofs) ? sdata[t - ofs] : 0;
        __syncthreads();
        sdata[t] += v;
        __syncthreads();
    }
    int run = (t > 0) ? sdata[t - 1] : 0;       // exclusive prefix
    for (int i = lo; i < hi; ++i) { off[b * NN + i] = run; run += cnt[b * NN + i]; }
}

__global__ __launch_bounds__(256) void fill_kernel(const int* __restrict__ ei,
                                                   const int* __restrict__ off,
                                                   int* __restrict__ cursor,
                                                   int* __restrict__ csr)
{
    int b = blockIdx.x & 15;
    int e = (blockIdx.x >> 4) * 256 + threadIdx.x;
    const int* eb = ei + (size_t)b * 2 * NE;
    int s = eb[e];
    int d = eb[NE + e];
    int pos = atomicAdd(&cursor[b * NN + d], 1);
    csr[(size_t)b * NE + off[b * NN + d] + pos] = s;
}

// ---------------- mean aggregation: wave per node, lane per channel ----------------
__global__ __launch_bounds__(256) void agg_kernel(const float* __restrict__ x,
                                                  const int* __restrict__ cnt,
                                                  const int* __restrict__ off,
                                                  const int* __restrict__ csr,
                                                  float* __restrict__ agg)
{
    int b = blockIdx.x & 15;                        // XCD affinity
    int chunk = blockIdx.x >> 4;                    // 0..2499
    int wid = threadIdx.x >> 6;                     // 4 waves = 4 nodes per block
    int n = chunk * 4 + wid;                        // 0..9999
    int w = b * NN + n;
    w = __builtin_amdgcn_readfirstlane(w);          // force wave-uniform -> scalar loads
    int lane = threadIdx.x & 63;
    int c = cnt[w];
    int o = off[w];
    const int* row = csr + (size_t)b * NE + o;
    const float* xb = x + (size_t)b * NN * HF;
    float s = 0.f;
    int t = 0;
    for (; t + 4 <= c; t += 4) {
        int i0 = row[t], i1 = row[t+1], i2 = row[t+2], i3 = row[t+3];
        s += xb[(size_t)i0 * HF + lane];
        s += xb[(size_t)i1 * HF + lane];
        s += xb[(size_t)i2 * HF + lane];
        s += xb[(size_t)i3 * HF + lane];
    }
    for (; t < c; ++t) s += xb[(size_t)row[t] * HF + lane];
    agg[(size_t)w * HF + lane] = (c > 0) ? s / (float)c : 0.f;
}

// ---------------- conv: [x,agg]@W + b, +residual, LN, relu (in-place on x) ----------------
__global__ __launch_bounds__(256) void conv_kernel(
    float* __restrict__ x, const float* __restrict__ agg,
    const float* __restrict__ W, const float* __restrict__ bias,
    const float* __restrict__ g, const float* __restrict__ beta)
{
    int node = blockIdx.x * 256 + threadIdx.x;
    const float* arow = agg + (size_t)node * HF;
    const float* xrow = x   + (size_t)node * HF;

    float acc[HF];
#pragma unroll
    for (int j = 0; j < HF; ++j) acc[j] = bias[j];

    // agg half: W rows 64..127
#pragma unroll 1
    for (int kc = 0; kc < HF; kc += 8) {
        float4 v0 = *(const float4*)(arow + kc);
        float4 v1 = *(const float4*)(arow + kc + 4);
        float av[8] = {v0.x, v0.y, v0.z, v0.w, v1.x, v1.y, v1.z, v1.w};
#pragma unroll
        for (int u = 0; u < 8; ++u) {
            const float* wr = W + (HF + kc + u) * HF;
#pragma unroll
            for (int j = 0; j < HF; ++j) acc[j] = fmaf(av[u], wr[j], acc[j]);
        }
    }

    // x half: W rows 0..63
#pragma unroll 1
    for (int kc = 0; kc < HF; kc += 8) {
        float4 v0 = *(const float4*)(xrow + kc);
        float4 v1 = *(const float4*)(xrow + kc + 4);
        float av[8] = {v0.x, v0.y, v0.z, v0.w, v1.x, v1.y, v1.z, v1.w};
#pragma unroll
        for (int u = 0; u < 8; ++u) {
            const float* wr = W + (kc + u) * HF;
#pragma unroll
            for (int j = 0; j < HF; ++j) acc[j] = fmaf(av[u], wr[j], acc[j]);
        }
    }

    // residual: reload x row (L1 hit), constant-indexed 4 at a time
#pragma unroll
    for (int q = 0; q < 16; ++q) {
        float4 r = ((const float4*)xrow)[q];
        acc[4*q]   += r.x; acc[4*q+1] += r.y;
        acc[4*q+2] += r.z; acc[4*q+3] += r.w;
    }

    // LayerNorm + relu, per-thread in registers
    float mu = 0.f;
#pragma unroll
    for (int j = 0; j < HF; ++j) mu += acc[j];
    mu *= (1.f / HF);
    float var = 0.f;
#pragma unroll
    for (int j = 0; j < HF; ++j) { float d = acc[j] - mu; var += d * d; }
    var *= (1.f / HF);
    float rs = rsqrtf(var + LN_EPS);
#pragma unroll
    for (int j = 0; j < HF; ++j) {
        float y = (acc[j] - mu) * rs * g[j] + beta[j];
        acc[j] = fmaxf(y, 0.f);
    }

    float4* dst = (float4*)(x + (size_t)node * HF);
#pragma unroll
    for (int q = 0; q < 16; ++q) {
        float4 v; v.x = acc[4*q]; v.y = acc[4*q+1]; v.z = acc[4*q+2]; v.w = acc[4*q+3];
        dst[q] = v;
    }
}

// ---------------- output head: out = x@out_w + out_b ----------------
__global__ __launch_bounds__(256) void out_kernel(const float* __restrict__ x,
                                                  const float* __restrict__ W,
                                                  const float* __restrict__ bias,
                                                  float* __restrict__ out)
{
    int node = blockIdx.x * 256 + threadIdx.x;
    const float* row = x + (size_t)node * HF;

    float o[OUTF];
#pragma unroll
    for (int j = 0; j < OUTF; ++j) o[j] = bias[j];

#pragma unroll 1
    for (int kc = 0; kc < HF; kc += 8) {
        float4 v0 = *(const float4*)(row + kc);
        float4 v1 = *(const float4*)(row + kc + 4);
        float av[8] = {v0.x, v0.y, v0.z, v0.w, v1.x, v1.y, v1.z, v1.w};
#pragma unroll
        for (int u = 0; u < 8; ++u) {
            const float* wr = W + (kc + u) * OUTF;
#pragma unroll
            for (int j = 0; j < OUTF; ++j) o[j] = fmaf(av[u], wr[j], o[j]);
        }
    }

    float4* dst = (float4*)(out + (size_t)node * OUTF);
#pragma unroll
    for (int q = 0; q < 8; ++q) {
        float4 v; v.x = o[4*q]; v.y = o[4*q+1]; v.z = o[4*q+2]; v.w = o[4*q+3];
        dst[q] = v;
    }
}

extern "C" void kernel_launch(void* const* d_in, const int* in_sizes, int n_in,
                              void* d_out, int out_size, void* d_ws, size_t ws_size,
                              hipStream_t stream)
{
    const float* nf     = (const float*)d_in[0];
    const int*   ei     = (const int*)  d_in[1];   // edge_indices (B,2,E), integer
    const float* enc_w1 = (const float*)d_in[3];
    const float* enc_b1 = (const float*)d_in[4];
    const float* enc_w2 = (const float*)d_in[5];
    const float* enc_b2 = (const float*)d_in[6];
    const float* conv_w = (const float*)d_in[7];   // (3,128,64)
    const float* conv_b = (const float*)d_in[8];   // (3,64)
    const float* ln_g   = (const float*)d_in[9];
    const float* ln_b   = (const float*)d_in[10];
    const float* out_w  = (const float*)d_in[11];  // (64,32)
    const float* out_b  = (const float*)d_in[12];

    // workspace layout (~94 MB)
    char* w = (char*)d_ws;
    float* x    = (float*)w; w += (size_t)NODES * HF * sizeof(float);   // 40.96 MB
    float* agg  = (float*)w; w += (size_t)NODES * HF * sizeof(float);   // 40.96 MB
    int* cnt    = (int*)w;   w += (size_t)NODES * sizeof(int);
    int* cursor = (int*)w;   w += (size_t)NODES * sizeof(int);          // adjacent to cnt
    int* off    = (int*)w;   w += (size_t)NODES * sizeof(int);
    int* csr    = (int*)w;                                              // 10.24 MB

    // zero cnt+cursor (one contiguous memset; ws is poisoned 0xAA every call)
    hipMemsetAsync(cnt, 0, (size_t)NODES * 2 * sizeof(int), stream);

    enc1_kernel<<<NODES / 256, 256, 0, stream>>>(nf, enc_w1, enc_b1, x);
    gemm64_kernel<<<NODES / 256, 256, 0, stream>>>(x, enc_w2, enc_b2);
    hist_kernel<<<NB * (NE / 256), 256, 0, stream>>>(ei, cnt);
    scan_kernel<<<NB, 256, 0, stream>>>(cnt, off);
    fill_kernel<<<NB * (NE / 256), 256, 0, stream>>>(ei, off, cursor, csr);

    for (int l = 0; l < 3; ++l) {
        agg_kernel<<<NODES / 4, 256, 0, stream>>>(x, cnt, off, csr, agg);
        conv_kernel<<<NODES / 256, 256, 0, stream>>>(x, agg,
                                                     conv_w + (size_t)l * 2 * HF * HF,
                                                     conv_b + (size_t)l * HF,
                                                     ln_g + (size_t)l * HF,
                                                     ln_b + (size_t)l * HF);
    }
    out_kernel<<<NODES / 256, 256, 0, stream>>>(x, out_w, out_b, (float*)d_out);
}